// Round 7
// baseline (192.279 us; speedup 1.0000x reference)
//
#include <hip/hip_runtime.h>
#include <hip/hip_bf16.h>

typedef __attribute__((ext_vector_type(8))) short bf16x8;
typedef __attribute__((ext_vector_type(4))) float f32x4;

#define NCOLP 384                 // padded columns (352 real + 32 zero)
#define STEP_SHORTS (NCOLP * 32)  // 12288 shorts = 24576 B per 32-k step
#define STEP_BYTES 24576
#define SEG_BYTES 6144            // per-ablk segment: 384 cols * 8k * 2B
#define NSTEP 32
#define BROWS 65536
#define A_SLOT 8192               // 64 rows * 128 B per k-step slot

static __device__ __forceinline__ unsigned int bf16rne(float f) {
  unsigned int u = __float_as_uint(f);
  return (u + 0x7FFFu + ((u >> 16) & 1u)) >> 16;
}
static __device__ __forceinline__ unsigned int pack2(float a, float b) {
  return bf16rne(a) | (bf16rne(b) << 16);
}
static __device__ __forceinline__ void gload16(const void* g, void* l) {
  __builtin_amdgcn_global_load_lds(
      (const __attribute__((address_space(1))) unsigned int*)g,
      (__attribute__((address_space(3))) unsigned int*)l, 16, 0, 0);
}

// Wpack layout: [step][ablk(4)][col(384)][k%8]  (bf16), step = 24576 B.
// Column map: [0,100) task0 (e*10+h), [100,200) task1, [200,300) shared,
// [300,340) gates (t*20+g), [340,384) zero pad.
__global__ void ple_prep(const float* __restrict__ Ws, const float* __restrict__ bs,
                         const float* __restrict__ Wt, const float* __restrict__ bt,
                         const float* __restrict__ Wg, const float* __restrict__ bg,
                         unsigned short* __restrict__ Wpack, float* __restrict__ bias) {
  const int n = blockIdx.x;  // 0..383
  const int tid = threadIdx.x;
  const float* src = nullptr;
  int stride = 0;
  float bval = 0.f;
  if (n < 200) {
    int t = n / 100, m = n % 100, e = m / 10, h = m % 10;
    src = Wt + (size_t)(t * 10 + e) * 10240 + h;
    stride = 10;
    bval = bt[(t * 10 + e) * 10 + h];
  } else if (n < 300) {
    int m = n - 200, e = m / 10, h = m % 10;
    src = Ws + (size_t)e * 10240 + h;
    stride = 10;
    bval = bs[e * 10 + h];
  } else if (n < 340) {
    int m = n - 300, t = m / 20, g = m % 20;
    src = Wg + (size_t)t * 20480 + g;
    stride = 20;
    bval = bg[t * 20 + g];
  }
  for (int j = 0; j < 4; j++) {
    int k = tid + j * 256;
    float v = src ? src[(size_t)k * stride] : 0.f;
    Wpack[(size_t)(k >> 5) * STEP_SHORTS + ((k >> 3) & 3) * (NCOLP * 8) + n * 8 +
          (k & 7)] = (unsigned short)bf16rne(v);
  }
  if (tid == 0 && n < 352) bias[n] = bval;
}

// Main: 512 threads = 8 waves (2M x 4N), 64 rows/block, 1024 blocks.
// A: global -> LDS 4-slot ring (global_load_lds, XOR source swizzle),
//    stage depth 3 iters (~>900cy HBM latency hidden).
// B: register double-bank from L2-resident Wpack (static indexing).
// Budget: acc 48 + B 48 + addr ~25 <= 128 VGPR -> 2 blocks/CU, no spill.
__global__ __launch_bounds__(512, 2) void ple_main(
    const float* __restrict__ x, const unsigned short* __restrict__ Wpack,
    const float* __restrict__ bias, const float* __restrict__ Wc,
    const float* __restrict__ bc, const float* __restrict__ Wv,
    const float* __restrict__ bv, float* __restrict__ out) {
  __shared__ __align__(16) char smem[45696];  // ring = first 32768 B; z aliases
  float* z = (float*)smem;                    // [32][357] epilogue

  const int tid = threadIdx.x;
  const int l = tid & 63, w = tid >> 6;
  const int wm = w >> 2, wn = w & 3;  // 2M x 4N
  const int arow = l & 15, ablk = l >> 4;
  const int rowbase = blockIdx.x * 64;

  const f32x4 fzero = {0.f, 0.f, 0.f, 0.f};
  f32x4 acc[2][6];
#pragma unroll
  for (int i = 0; i < 2; ++i)
#pragma unroll
    for (int j = 0; j < 6; ++j) acc[i][j] = fzero;

  // ---- A staging: 1 chunk (16B) per thread per k-step ----
  // LDS chunk c = tid: row = c>>3, phys col s' = c&7; holds logical slot
  // s = s' ^ (row&7). Source = x[rowbase+row][ks*32 + s*4 floats].
  const int srow = tid >> 3;
  const int slog = (tid & 7) ^ (srow & 7);
  const char* asrc = (const char*)x + (size_t)(rowbase + srow) * 4096 + slog * 16;
  char* adst = smem + tid * 16;  // + slot*A_SLOT

  // ---- A fragment reads: row_local = wm*32 + mf*16 + arow ----
  const int sp0 = ((ablk * 2) ^ (arow & 7)) * 16;
  const int sp1 = ((ablk * 2 + 1) ^ (arow & 7)) * 16;
  const int arbase = (wm * 32 + arow) * 128;

  // ---- B fragment base (per-lane 16B from Wpack) ----
  const char* bbase = (const char*)Wpack + ablk * SEG_BYTES +
                      (wn * 96 + arow) * 16;

  bf16x8 b0[6], b1[6];  // named banks, static indexing only

  // ---- prologue: stage A(0..2) -> slots 0..2; load B(0) -> b0 ----
  gload16(asrc, adst);
  gload16(asrc + 128, adst + A_SLOT);
  gload16(asrc + 256, adst + 2 * A_SLOT);
  __builtin_amdgcn_sched_barrier(0);
#pragma unroll
  for (int nt = 0; nt < 6; nt++)
    b0[nt] = *(const bf16x8*)(bbase + nt * 256);
  __builtin_amdgcn_sched_barrier(0);

  // Per iter: 1 stage + 6 B = 7 vmem. B(ks) has exactly 7 younger ops at
  // the wait -> vmcnt(7); A(ks) staged 3 iters ago is far older.
#define KSTEP(ks, SRD, SWR, bc_, bn_)                                          \
  {                                                                            \
    const int ksA = ((ks) + 3 < NSTEP) ? (ks) + 3 : NSTEP - 1;                 \
    gload16(asrc + (size_t)ksA * 128, adst + (SWR)*A_SLOT);                    \
    __builtin_amdgcn_sched_barrier(0);                                         \
    const int ksB = ((ks) + 1 < NSTEP) ? (ks) + 1 : NSTEP - 1;                 \
    const char* bp = bbase + (size_t)ksB * STEP_BYTES;                         \
    _Pragma("unroll") for (int nt = 0; nt < 6; nt++)                           \
        bn_[nt] = *(const bf16x8*)(bp + nt * 256);                             \
    __builtin_amdgcn_sched_barrier(0);                                         \
    asm volatile("s_waitcnt vmcnt(7)" ::: "memory");                           \
    __builtin_amdgcn_s_barrier();                                              \
    __builtin_amdgcn_sched_barrier(0);                                         \
    const char* ab = smem + (SRD)*A_SLOT + arbase;                             \
    _Pragma("unroll") for (int mf = 0; mf < 2; mf++) {                         \
      float4 fa = *(const float4*)(ab + mf * 2048 + sp0);                      \
      float4 fb = *(const float4*)(ab + mf * 2048 + sp1);                      \
      union { bf16x8 v; uint4 u; } A;                                          \
      A.u = make_uint4(pack2(fa.x, fa.y), pack2(fa.z, fa.w),                   \
                       pack2(fb.x, fb.y), pack2(fb.z, fb.w));                  \
      _Pragma("unroll") for (int nt = 0; nt < 6; nt++)                         \
          acc[mf][nt] = __builtin_amdgcn_mfma_f32_16x16x32_bf16(               \
              A.v, bc_[nt], acc[mf][nt], 0, 0, 0);                             \
    }                                                                          \
    __builtin_amdgcn_sched_barrier(0);                                         \
    __builtin_amdgcn_s_barrier();                                              \
  }

  for (int kk = 0; kk < NSTEP / 4; kk++) {
    KSTEP(4 * kk + 0, 0, 3, b0, b1)
    KSTEP(4 * kk + 1, 1, 0, b1, b0)
    KSTEP(4 * kk + 2, 2, 1, b0, b1)
    KSTEP(4 * kk + 3, 3, 2, b1, b0)
  }
#undef KSTEP

  // Drain redundant tail stages before z overwrites the ring.
  asm volatile("s_waitcnt vmcnt(0)" ::: "memory");

  // ---- epilogue: 2 phases of 32 rows. D layout: row=(l>>4)*4+reg, col=l&15.
#pragma unroll
  for (int p = 0; p < 2; p++) {
    __syncthreads();
    if (wm == p) {
#pragma unroll
      for (int mf = 0; mf < 2; mf++) {
#pragma unroll
        for (int nt = 0; nt < 6; nt++) {
          if (wn == 3 && nt >= 4) continue;  // cols >= 352 are zero pad
#pragma unroll
          for (int r = 0; r < 4; r++)
            z[(mf * 16 + ablk * 4 + r) * 357 + wn * 96 + nt * 16 + arow] =
                acc[mf][nt][r];
        }
      }
    }
    __syncthreads();
    if (tid < 64) {
      const int t = tid >> 5, r = tid & 31;
      const float* zr = &z[r * 357];
      float gl[20], m = -1e30f;
#pragma unroll
      for (int u = 0; u < 20; u++) {
        gl[u] = zr[300 + t * 20 + u] + bias[300 + t * 20 + u];
        m = fmaxf(m, gl[u]);
      }
      float pr[20], s = 0.f;
#pragma unroll
      for (int u = 0; u < 20; u++) {
        pr[u] = __expf(gl[u] - m);
        s += pr[u];
      }
      const float inv = 1.f / s;
      const float* Wl = t ? Wv : Wc;
      float wl[10];
#pragma unroll
      for (int h = 0; h < 10; h++) wl[h] = Wl[h];
      float accum = 0.f;
#pragma unroll
      for (int u = 0; u < 10; u++) {
        float d = 0.f;
#pragma unroll
        for (int h = 0; h < 10; h++) {
          int c = t * 100 + u * 10 + h;
          d += fmaxf(zr[c] + bias[c], 0.f) * wl[h];
        }
        accum += pr[u] * d;
      }
#pragma unroll
      for (int u = 0; u < 10; u++) {
        float d = 0.f;
#pragma unroll
        for (int h = 0; h < 10; h++) {
          int c = 200 + u * 10 + h;
          d += fmaxf(zr[c] + bias[c], 0.f) * wl[h];
        }
        accum += pr[10 + u] * d;
      }
      float logit = (t ? bv[0] : bc[0]) + accum * inv;
      out[(size_t)t * BROWS + rowbase + p * 32 + r] =
          1.f / (1.f + __expf(-logit));
    }
  }
}

extern "C" void kernel_launch(void* const* d_in, const int* in_sizes, int n_in,
                              void* d_out, int out_size, void* d_ws, size_t ws_size,
                              hipStream_t stream) {
  const float* x = (const float*)d_in[0];
  const float* Ws = (const float*)d_in[3];
  const float* bs = (const float*)d_in[4];
  const float* Wt = (const float*)d_in[5];
  const float* bt = (const float*)d_in[6];
  const float* Wg = (const float*)d_in[7];
  const float* bg = (const float*)d_in[8];
  const float* Wc = (const float*)d_in[9];
  const float* bc = (const float*)d_in[10];
  const float* Wv = (const float*)d_in[11];
  const float* bv = (const float*)d_in[12];
  unsigned short* Wpack = (unsigned short*)d_ws;
  float* bias = (float*)((char*)d_ws + (size_t)NCOLP * 1024 * 2);
  float* out = (float*)d_out;

  hipLaunchKernelGGL(ple_prep, dim3(NCOLP), dim3(256), 0, stream, Ws, bs, Wt, bt,
                     Wg, bg, Wpack, bias);
  hipLaunchKernelGGL(ple_main, dim3(BROWS / 64), dim3(512), 0, stream, x, Wpack,
                     bias, Wc, bc, Wv, bv, out);
}

// Round 8
// 140.443 us; speedup vs baseline: 1.3691x; 1.3691x over previous
//
#include <hip/hip_runtime.h>
#include <hip/hip_bf16.h>

typedef __attribute__((ext_vector_type(8))) short bf16x8;
typedef __attribute__((ext_vector_type(4))) float f32x4;

#define NCOLP 384                 // padded columns (352 real + 32 zero)
#define STEP_SHORTS (NCOLP * 32)  // 12288 shorts = 24576 B per 32-k step
#define STEP_BYTES 24576
#define NSTEP 32
#define BROWS 65536
#define A_SLOT 8192               // 64 rows * 128 B fp32 per k-step
#define B_SLOT 24640              // 24576 + 4*16 per-ablk pad
#define SLOT (A_SLOT + B_SLOT)    // 32832

static __device__ __forceinline__ unsigned int bf16rne(float f) {
  unsigned int u = __float_as_uint(f);
  return (u + 0x7FFFu + ((u >> 16) & 1u)) >> 16;
}
static __device__ __forceinline__ unsigned int pack2(float a, float b) {
  return bf16rne(a) | (bf16rne(b) << 16);
}
static __device__ __forceinline__ void gload16(const void* g, void* l) {
  __builtin_amdgcn_global_load_lds(
      (const __attribute__((address_space(1))) unsigned int*)g,
      (__attribute__((address_space(3))) unsigned int*)l, 16, 0, 0);
}

// Wpack layout: [step][ablk(4)][col(384)][k%8] (bf16), 24576 B/step.
// Column map: [0,100) task0 (e*10+h), [100,200) task1, [200,300) shared,
// [300,340) gates (t*20+g), [340,384) zero pad.
__global__ void ple_prep(const float* __restrict__ Ws, const float* __restrict__ bs,
                         const float* __restrict__ Wt, const float* __restrict__ bt,
                         const float* __restrict__ Wg, const float* __restrict__ bg,
                         unsigned short* __restrict__ Wpack, float* __restrict__ bias) {
  const int n = blockIdx.x;  // 0..383
  const int tid = threadIdx.x;
  const float* src = nullptr;
  int stride = 0;
  float bval = 0.f;
  if (n < 200) {
    int t = n / 100, m = n % 100, e = m / 10, h = m % 10;
    src = Wt + (size_t)(t * 10 + e) * 10240 + h;
    stride = 10;
    bval = bt[(t * 10 + e) * 10 + h];
  } else if (n < 300) {
    int m = n - 200, e = m / 10, h = m % 10;
    src = Ws + (size_t)e * 10240 + h;
    stride = 10;
    bval = bs[e * 10 + h];
  } else if (n < 340) {
    int m = n - 300, t = m / 20, g = m % 20;
    src = Wg + (size_t)t * 20480 + g;
    stride = 20;
    bval = bg[t * 20 + g];
  }
  for (int j = 0; j < 4; j++) {
    int k = tid + j * 256;
    float v = src ? src[(size_t)k * stride] : 0.f;
    Wpack[(size_t)(k >> 5) * STEP_SHORTS + ((k >> 3) & 3) * (NCOLP * 8) + n * 8 +
          (k & 7)] = (unsigned short)bf16rne(v);
  }
  if (tid == 0 && n < 352) bias[n] = bval;
}

// Main: 512 threads = 8 waves (1M x 8N), 64 rows/block, 1024 blocks.
// m97 structure: A and B both global_load_lds into double-buffered LDS,
// plain __syncthreads() per K-step; latency hidden by 2 blocks/CU TLP.
__global__ __launch_bounds__(512, 4) void ple_main(
    const float* __restrict__ x, const unsigned short* __restrict__ Wpack,
    const float* __restrict__ bias, const float* __restrict__ Wc,
    const float* __restrict__ bc, const float* __restrict__ Wv,
    const float* __restrict__ bv, float* __restrict__ out) {
  __shared__ __align__(16) char smem[2 * SLOT];  // 65664 B; z[32][357] aliases
  float* z = (float*)smem;

  const int tid = threadIdx.x;
  const int l = tid & 63, w = tid >> 6;  // wave = N-slice (48 cols each)
  const int arow = l & 15, ablk = l >> 4;
  const int rowbase = blockIdx.x * 64;

  const f32x4 fzero = {0.f, 0.f, 0.f, 0.f};
  f32x4 acc[4][3];
#pragma unroll
  for (int i = 0; i < 4; ++i)
#pragma unroll
    for (int j = 0; j < 3; ++j) acc[i][j] = fzero;

  // ---- A staging: chunk = tid (512 x 16B). row=tid>>3, phys col'=tid&7
  // holds logical col (tid&7)^(row&7). src = x[row][ks*32 + lcol*4 floats].
  const int srow = tid >> 3;
  const int slcol = (tid & 7) ^ (srow & 7);
  const char* asrc = (const char*)x + (size_t)(rowbase + srow) * 4096 + slcol * 16;
  char* adst = smem + tid * 16;  // + slot*SLOT

  // ---- B staging: 3 chunks c = tid + j*512; straight copy + ablk pad.
  const char* bsrc = (const char*)Wpack;
  // dst offset for chunk c: A_SLOT + c*16 + (c/384)*16

  // ---- A fragment reads: per mf, row_local = mf*16 + arow ----
  const int sp0 = ((ablk * 2) ^ (arow & 7)) * 16;
  const int sp1 = ((ablk * 2 + 1) ^ (arow & 7)) * 16;

  // ---- B fragment base: ablk*6160 + (w*48 + nt*16 + arow)*16 ----
  const int brd = A_SLOT + ablk * 6160 + (w * 48 + arow) * 16;

  // ---- prologue: stage tile 0 -> slot 0 ----
  {
    gload16(asrc, adst);
#pragma unroll
    for (int j = 0; j < 3; j++) {
      const int c = tid + j * 512;
      gload16(bsrc + c * 16, smem + A_SLOT + c * 16 + (c / 384) * 16);
    }
  }
  __syncthreads();

  for (int ks = 0; ks < NSTEP; ks++) {
    const int cur = ks & 1;
    // stage next tile into the other slot
    if (ks + 1 < NSTEP) {
      const size_t so = (size_t)(cur ^ 1) * SLOT;
      gload16(asrc + (size_t)(ks + 1) * 128, adst + so);
      const char* bstep = bsrc + (size_t)(ks + 1) * STEP_BYTES;
#pragma unroll
      for (int j = 0; j < 3; j++) {
        const int c = tid + j * 512;
        gload16(bstep + c * 16, smem + so + A_SLOT + c * 16 + (c / 384) * 16);
      }
    }
    // compute from slot cur
    {
      const char* base = smem + (size_t)cur * SLOT;
      const char* bb = base + brd;
      bf16x8 bf0 = *(const bf16x8*)(bb);
      bf16x8 bf1 = *(const bf16x8*)(bb + 256);
      bf16x8 bf2 = *(const bf16x8*)(bb + 512);
#pragma unroll
      for (int mf = 0; mf < 4; mf++) {
        const char* ab = base + (mf * 16 + arow) * 128;
        float4 fa = *(const float4*)(ab + sp0);
        float4 fb = *(const float4*)(ab + sp1);
        union { bf16x8 v; uint4 u; } A;
        A.u = make_uint4(pack2(fa.x, fa.y), pack2(fa.z, fa.w),
                         pack2(fb.x, fb.y), pack2(fb.z, fb.w));
        acc[mf][0] = __builtin_amdgcn_mfma_f32_16x16x32_bf16(A.v, bf0, acc[mf][0], 0, 0, 0);
        acc[mf][1] = __builtin_amdgcn_mfma_f32_16x16x32_bf16(A.v, bf1, acc[mf][1], 0, 0, 0);
        acc[mf][2] = __builtin_amdgcn_mfma_f32_16x16x32_bf16(A.v, bf2, acc[mf][2], 0, 0, 0);
      }
    }
    __syncthreads();  // drains vmcnt/lgkmcnt: staged tile ready, slot reads done
  }

  // ---- epilogue: 2 phases of 32 rows. D layout: row=(l>>4)*4+reg, col=l&15.
#pragma unroll
  for (int p = 0; p < 2; p++) {
    __syncthreads();
#pragma unroll
    for (int q = 0; q < 2; q++) {
      const int mf = p * 2 + q;
#pragma unroll
      for (int nt = 0; nt < 3; nt++) {
        if (w == 7 && nt >= 1) continue;  // cols >= 352 are zero pad
#pragma unroll
        for (int r = 0; r < 4; r++)
          z[(q * 16 + ablk * 4 + r) * 357 + w * 48 + nt * 16 + arow] =
              acc[mf][nt][r];
      }
    }
    __syncthreads();
    if (tid < 64) {
      const int t = tid >> 5, r = tid & 31;
      const float* zr = &z[r * 357];
      float gl[20], m = -1e30f;
#pragma unroll
      for (int u = 0; u < 20; u++) {
        gl[u] = zr[300 + t * 20 + u] + bias[300 + t * 20 + u];
        m = fmaxf(m, gl[u]);
      }
      float pr[20], s = 0.f;
#pragma unroll
      for (int u = 0; u < 20; u++) {
        pr[u] = __expf(gl[u] - m);
        s += pr[u];
      }
      const float inv = 1.f / s;
      const float* Wl = t ? Wv : Wc;
      float wl[10];
#pragma unroll
      for (int h = 0; h < 10; h++) wl[h] = Wl[h];
      float accum = 0.f;
#pragma unroll
      for (int u = 0; u < 10; u++) {
        float d = 0.f;
#pragma unroll
        for (int h = 0; h < 10; h++) {
          int c = t * 100 + u * 10 + h;
          d += fmaxf(zr[c] + bias[c], 0.f) * wl[h];
        }
        accum += pr[u] * d;
      }
#pragma unroll
      for (int u = 0; u < 10; u++) {
        float d = 0.f;
#pragma unroll
        for (int h = 0; h < 10; h++) {
          int c = 200 + u * 10 + h;
          d += fmaxf(zr[c] + bias[c], 0.f) * wl[h];
        }
        accum += pr[10 + u] * d;
      }
      float logit = (t ? bv[0] : bc[0]) + accum * inv;
      out[(size_t)t * BROWS + rowbase + p * 32 + r] =
          1.f / (1.f + __expf(-logit));
    }
  }
}

extern "C" void kernel_launch(void* const* d_in, const int* in_sizes, int n_in,
                              void* d_out, int out_size, void* d_ws, size_t ws_size,
                              hipStream_t stream) {
  const float* x = (const float*)d_in[0];
  const float* Ws = (const float*)d_in[3];
  const float* bs = (const float*)d_in[4];
  const float* Wt = (const float*)d_in[5];
  const float* bt = (const float*)d_in[6];
  const float* Wg = (const float*)d_in[7];
  const float* bg = (const float*)d_in[8];
  const float* Wc = (const float*)d_in[9];
  const float* bc = (const float*)d_in[10];
  const float* Wv = (const float*)d_in[11];
  const float* bv = (const float*)d_in[12];
  unsigned short* Wpack = (unsigned short*)d_ws;
  float* bias = (float*)((char*)d_ws + (size_t)NCOLP * 1024 * 2);
  float* out = (float*)d_out;

  hipLaunchKernelGGL(ple_prep, dim3(NCOLP), dim3(256), 0, stream, Ws, bs, Wt, bt,
                     Wg, bg, Wpack, bias);
  hipLaunchKernelGGL(ple_main, dim3(BROWS / 64), dim3(512), 0, stream, x, Wpack,
                     bias, Wc, bc, Wv, bv, out);
}

// Round 9
// 108.853 us; speedup vs baseline: 1.7664x; 1.2902x over previous
//
#include <hip/hip_runtime.h>
#include <hip/hip_bf16.h>

typedef __attribute__((ext_vector_type(8))) short bf16x8;
typedef __attribute__((ext_vector_type(4))) float f32x4;

#define NCOLP 384                 // padded columns (352 real + 32 zero)
#define STEP_SHORTS (NCOLP * 32)  // 12288 shorts = 24576 B per 32-k step
#define STEP_BYTES 24576
#define NSTEP 32
#define BROWS 65536
#define A_SLOT 4224               // 4 kb-blocks * 1056 B (64 rows * 16B + 32 pad)
#define B_OFF 8448                // A ring = 2 * A_SLOT
#define B_SLOT 24640              // 24576 + 4*16 per-ablk pad
#define SMEM_SZ (B_OFF + 2 * B_SLOT)  // 57728

static __device__ __forceinline__ unsigned int bf16rne(float f) {
  unsigned int u = __float_as_uint(f);
  return (u + 0x7FFFu + ((u >> 16) & 1u)) >> 16;
}
static __device__ __forceinline__ unsigned int pack2(float a, float b) {
  return bf16rne(a) | (bf16rne(b) << 16);
}
static __device__ __forceinline__ void gload16(const void* g, void* l) {
  __builtin_amdgcn_global_load_lds(
      (const __attribute__((address_space(1))) unsigned int*)g,
      (__attribute__((address_space(3))) unsigned int*)l, 16, 0, 0);
}

// Wpack layout: [step][ablk(4)][col(384)][k%8] (bf16), 24576 B/step.
// Column map: [0,100) task0 (e*10+h), [100,200) task1, [200,300) shared,
// [300,340) gates (t*20+g), [340,384) zero pad.
__global__ void ple_prep(const float* __restrict__ Ws, const float* __restrict__ bs,
                         const float* __restrict__ Wt, const float* __restrict__ bt,
                         const float* __restrict__ Wg, const float* __restrict__ bg,
                         unsigned short* __restrict__ Wpack, float* __restrict__ bias) {
  const int n = blockIdx.x;  // 0..383
  const int tid = threadIdx.x;
  const float* src = nullptr;
  int stride = 0;
  float bval = 0.f;
  if (n < 200) {
    int t = n / 100, m = n % 100, e = m / 10, h = m % 10;
    src = Wt + (size_t)(t * 10 + e) * 10240 + h;
    stride = 10;
    bval = bt[(t * 10 + e) * 10 + h];
  } else if (n < 300) {
    int m = n - 200, e = m / 10, h = m % 10;
    src = Ws + (size_t)e * 10240 + h;
    stride = 10;
    bval = bs[e * 10 + h];
  } else if (n < 340) {
    int m = n - 300, t = m / 20, g = m % 20;
    src = Wg + (size_t)t * 20480 + g;
    stride = 20;
    bval = bg[t * 20 + g];
  }
  for (int j = 0; j < 4; j++) {
    int k = tid + j * 256;
    float v = src ? src[(size_t)k * stride] : 0.f;
    Wpack[(size_t)(k >> 5) * STEP_SHORTS + ((k >> 3) & 3) * (NCOLP * 8) + n * 8 +
          (k & 7)] = (unsigned short)bf16rne(v);
  }
  if (tid == 0 && n < 352) bias[n] = bval;
}

// Main: 512 threads = 8 waves (2M x 4N), 64 rows/block, 1024 blocks.
// A: global->reg (3-iter lead, 2 banks) -> cvt bf16 -> ds_write 2-slot ring.
// B: global_load_lds 2-slot ring (1-iter lead, L2-resident).
// Counted vmcnt(5) per iter keeps A(j+2),B(j+1),A(j+3) in flight across
// barriers; FIFO-checked so no premature drain of the HBM A-stream.
__global__ __launch_bounds__(512, 4) void ple_main(
    const float* __restrict__ x, const unsigned short* __restrict__ Wpack,
    const float* __restrict__ bias, const float* __restrict__ Wc,
    const float* __restrict__ bc, const float* __restrict__ Wv,
    const float* __restrict__ bv, float* __restrict__ out) {
  __shared__ __align__(16) char smem[SMEM_SZ];  // z[32][357] aliases front
  float* z = (float*)smem;

  const int tid = threadIdx.x;
  const int l = tid & 63, w = tid >> 6;
  const int wm = w >> 2, wn = w & 3;  // 2M x 4N
  const int arow = l & 15, ablk = l >> 4;
  const int rowbase = blockIdx.x * 64;

  const f32x4 fzero = {0.f, 0.f, 0.f, 0.f};
  f32x4 acc[2][6];
#pragma unroll
  for (int i = 0; i < 2; ++i)
#pragma unroll
    for (int j = 0; j < 6; ++j) acc[i][j] = fzero;

  // ---- A staging: thread -> (row = tid>>3, seg = tid&7 of 16B fp32) ----
  const int srow = tid >> 3, seg = tid & 7;
  const int kb = seg >> 1, hh = seg & 1;
  const char* asrc =
      (const char*)x + (size_t)(rowbase + srow) * 4096 + seg * 16;
  char* awr = smem + kb * 1056 + srow * 16 + hh * 8;  // + slot*A_SLOT

  // ---- B staging: 3 chunks c = tid + jj*512 (16B each) ----
  const char* wsrcB = (const char*)Wpack;
  const int bc0 = tid, bc1 = tid + 512, bc2 = tid + 1024;
  char* bdst0 = smem + B_OFF + bc0 * 16 + (bc0 / 384) * 16;
  char* bdst1 = smem + B_OFF + bc1 * 16 + (bc1 / 384) * 16;
  char* bdst2 = smem + B_OFF + bc2 * 16 + (bc2 / 384) * 16;

  // ---- fragment read bases ----
  const char* ard = smem + ablk * 1056 + wm * 512 + arow * 16;   // +mf*256
  const char* brd = smem + B_OFF + ablk * 6160 + (wn * 96 + arow) * 16;  // +nt*256

  // ---- prologue ----
  gload16(wsrcB + bc0 * 16, bdst0);  // B(0) -> slot 0
  gload16(wsrcB + bc1 * 16, bdst1);
  gload16(wsrcB + bc2 * 16, bdst2);
  __builtin_amdgcn_sched_barrier(0);
  float4 t0 = *(const float4*)(asrc);  // A(0)
  __builtin_amdgcn_sched_barrier(0);
  float4 bankA0 = *(const float4*)(asrc + 128);  // A(1)
  float4 bankA1 = *(const float4*)(asrc + 256);  // A(2)
  __builtin_amdgcn_sched_barrier(0);
  {
    uint2 wv;
    wv.x = pack2(t0.x, t0.y);
    wv.y = pack2(t0.z, t0.w);
    *(uint2*)(awr) = wv;  // A(0) -> slot 0  (compiler drains t0 + B(0))
  }
  asm volatile("s_waitcnt vmcnt(2) lgkmcnt(0)" ::: "memory");
  __builtin_amdgcn_s_barrier();
  __builtin_amdgcn_sched_barrier(0);

#define ITER(J, P, BK)                                                         \
  {                                                                            \
    const int tB = ((J) + 1 < NSTEP) ? (J) + 1 : NSTEP - 1;                    \
    const char* bs_ = wsrcB + (size_t)tB * STEP_BYTES;                         \
    gload16(bs_ + bc0 * 16, bdst0 + ((P) ^ 1) * B_SLOT);                       \
    gload16(bs_ + bc1 * 16, bdst1 + ((P) ^ 1) * B_SLOT);                       \
    gload16(bs_ + bc2 * 16, bdst2 + ((P) ^ 1) * B_SLOT);                       \
    __builtin_amdgcn_sched_barrier(0);                                         \
    {                                                                          \
      uint2 wv;                                                                \
      wv.x = pack2(BK.x, BK.y);                                                \
      wv.y = pack2(BK.z, BK.w);                                                \
      *(uint2*)(awr + ((P) ^ 1) * A_SLOT) = wv;                                \
    }                                                                          \
    __builtin_amdgcn_sched_barrier(0);                                         \
    {                                                                          \
      const int tA = ((J) + 3 < NSTEP) ? (J) + 3 : NSTEP - 1;                  \
      BK = *(const float4*)(asrc + (size_t)tA * 128);                          \
    }                                                                          \
    __builtin_amdgcn_sched_barrier(0);                                         \
    asm volatile("s_waitcnt vmcnt(5) lgkmcnt(0)" ::: "memory");                \
    __builtin_amdgcn_s_barrier();                                              \
    __builtin_amdgcn_sched_barrier(0);                                         \
    {                                                                          \
      const char* ar_ = ard + (P)*A_SLOT;                                      \
      const char* br_ = brd + (P)*B_SLOT;                                      \
      bf16x8 a0 = *(const bf16x8*)(ar_);                                       \
      bf16x8 a1 = *(const bf16x8*)(ar_ + 256);                                 \
      _Pragma("unroll") for (int nt = 0; nt < 6; nt++) {                       \
        bf16x8 bq = *(const bf16x8*)(br_ + nt * 256);                          \
        acc[0][nt] = __builtin_amdgcn_mfma_f32_16x16x32_bf16(                  \
            a0, bq, acc[0][nt], 0, 0, 0);                                      \
        acc[1][nt] = __builtin_amdgcn_mfma_f32_16x16x32_bf16(                  \
            a1, bq, acc[1][nt], 0, 0, 0);                                      \
      }                                                                        \
    }                                                                          \
    __builtin_amdgcn_sched_barrier(0);                                         \
    __builtin_amdgcn_s_barrier();                                              \
  }

  for (int jj = 0; jj < NSTEP / 2; jj++) {
    ITER(2 * jj, 0, bankA0)
    ITER(2 * jj + 1, 1, bankA1)
  }
#undef ITER

  __syncthreads();  // full drain (tail re-stages) before z aliases the ring

  // ---- epilogue: 2 phases of 32 rows. D layout: row=(l>>4)*4+reg, col=l&15.
#pragma unroll
  for (int p = 0; p < 2; p++) {
    __syncthreads();
    if (wm == p) {
#pragma unroll
      for (int mf = 0; mf < 2; mf++) {
#pragma unroll
        for (int nt = 0; nt < 6; nt++) {
          if (wn == 3 && nt >= 4) continue;  // cols >= 352 are zero pad
#pragma unroll
          for (int r = 0; r < 4; r++)
            z[(mf * 16 + ablk * 4 + r) * 357 + wn * 96 + nt * 16 + arow] =
                acc[mf][nt][r];
        }
      }
    }
    __syncthreads();
    if (tid < 64) {
      const int t = tid >> 5, r = tid & 31;
      const float* zr = &z[r * 357];
      float gl[20], m = -1e30f;
#pragma unroll
      for (int u = 0; u < 20; u++) {
        gl[u] = zr[300 + t * 20 + u] + bias[300 + t * 20 + u];
        m = fmaxf(m, gl[u]);
      }
      float pr[20], s = 0.f;
#pragma unroll
      for (int u = 0; u < 20; u++) {
        pr[u] = __expf(gl[u] - m);
        s += pr[u];
      }
      const float inv = 1.f / s;
      const float* Wl = t ? Wv : Wc;
      float wl[10];
#pragma unroll
      for (int h = 0; h < 10; h++) wl[h] = Wl[h];
      float accum = 0.f;
#pragma unroll
      for (int u = 0; u < 10; u++) {
        float d = 0.f;
#pragma unroll
        for (int h = 0; h < 10; h++) {
          int c = t * 100 + u * 10 + h;
          d += fmaxf(zr[c] + bias[c], 0.f) * wl[h];
        }
        accum += pr[u] * d;
      }
#pragma unroll
      for (int u = 0; u < 10; u++) {
        float d = 0.f;
#pragma unroll
        for (int h = 0; h < 10; h++) {
          int c = 200 + u * 10 + h;
          d += fmaxf(zr[c] + bias[c], 0.f) * wl[h];
        }
        accum += pr[10 + u] * d;
      }
      float logit = (t ? bv[0] : bc[0]) + accum * inv;
      out[(size_t)t * BROWS + rowbase + p * 32 + r] =
          1.f / (1.f + __expf(-logit));
    }
  }
}

extern "C" void kernel_launch(void* const* d_in, const int* in_sizes, int n_in,
                              void* d_out, int out_size, void* d_ws, size_t ws_size,
                              hipStream_t stream) {
  const float* x = (const float*)d_in[0];
  const float* Ws = (const float*)d_in[3];
  const float* bs = (const float*)d_in[4];
  const float* Wt = (const float*)d_in[5];
  const float* bt = (const float*)d_in[6];
  const float* Wg = (const float*)d_in[7];
  const float* bg = (const float*)d_in[8];
  const float* Wc = (const float*)d_in[9];
  const float* bc = (const float*)d_in[10];
  const float* Wv = (const float*)d_in[11];
  const float* bv = (const float*)d_in[12];
  unsigned short* Wpack = (unsigned short*)d_ws;
  float* bias = (float*)((char*)d_ws + (size_t)NCOLP * 1024 * 2);
  float* out = (float*)d_out;

  hipLaunchKernelGGL(ple_prep, dim3(NCOLP), dim3(256), 0, stream, Ws, bs, Wt, bt,
                     Wg, bg, Wpack, bias);
  hipLaunchKernelGGL(ple_main, dim3(BROWS / 64), dim3(512), 0, stream, x, Wpack,
                     bias, Wc, bc, Wv, bv, out);
}